// Round 1
// 577.723 us; speedup vs baseline: 1.0428x; 1.0428x over previous
//
#include <hip/hip_runtime.h>
#include <math.h>

#define B_   8
#define C_   512
#define L_   4096
#define H_   8
#define DK_  64
#define C2_  1024

typedef unsigned short ushort;
typedef short     bf16x8_t __attribute__((ext_vector_type(8)));
typedef float     f32x4_t  __attribute__((ext_vector_type(4)));
typedef unsigned short u16x8 __attribute__((ext_vector_type(8)));
typedef unsigned short u16x4 __attribute__((ext_vector_type(4)));

__device__ __forceinline__ float bf2f(ushort u) {
    unsigned int x = ((unsigned int)u) << 16;
    float f; __builtin_memcpy(&f, &x, 4); return f;
}
__device__ __forceinline__ ushort f2bf(float f) {
    unsigned int x; __builtin_memcpy(&x, &f, 4);
    x = (x + 0x7FFFu + ((x >> 16) & 1u)) >> 16;   // RNE
    return (ushort)x;
}

#define GLOAD_LDS16(gp, lp) \
    __builtin_amdgcn_global_load_lds((const __attribute__((address_space(1))) void*)(gp), \
                                     (__attribute__((address_space(3))) void*)(lp), 16, 0, 0)

// ---------------------------------------------------------------------------
// transpose_in: fp32 [B,C,L] -> bf16 [B*L, C].  grid (L/64, C/64, B), 256 thr
// ---------------------------------------------------------------------------
__global__ __launch_bounds__(256) void transpose_in(const float* __restrict__ in,
                                                    ushort* __restrict__ out)
{
    const int b = blockIdx.z, c0 = blockIdx.y * 64, l0 = blockIdx.x * 64;
    __shared__ float t[64][65];
    const int tid = threadIdx.x;
    {
        const int c = tid >> 4, l4 = (tid & 15) * 4;
        const float* ip = in + ((size_t)b * C_ + c0) * L_ + l0;
#pragma unroll
        for (int cc = c; cc < 64; cc += 16) {
            float4 v = *(const float4*)(ip + (size_t)cc * L_ + l4);
            t[l4 + 0][cc] = v.x; t[l4 + 1][cc] = v.y;
            t[l4 + 2][cc] = v.z; t[l4 + 3][cc] = v.w;
        }
    }
    __syncthreads();
    {
        const int l = tid >> 3, c8 = (tid & 7) * 8;
        ushort* op = out + ((size_t)b * L_ + l0) * C_ + c0;
#pragma unroll
        for (int ll = l; ll < 64; ll += 32) {
            u16x8 v;
#pragma unroll
            for (int i = 0; i < 8; ++i) v[i] = f2bf(t[ll][c8 + i]);
            *(u16x8*)(op + (size_t)ll * C_ + c8) = v;
        }
    }
}

// ---------------------------------------------------------------------------
// transpose_out: fp32 [B*L, C] -> fp32 [B,C,L].  grid (L/64, C/64, B)
// ---------------------------------------------------------------------------
__global__ __launch_bounds__(256) void transpose_out(const float* __restrict__ in,
                                                     float* __restrict__ out)
{
    const int b = blockIdx.z, c0 = blockIdx.y * 64, l0 = blockIdx.x * 64;
    __shared__ float t[64][65];   // t[c][l]
    const int tid = threadIdx.x;
    {
        const int l = tid >> 4, c4 = (tid & 15) * 4;
#pragma unroll
        for (int ll = l; ll < 64; ll += 16) {
            float4 v = *(const float4*)(in + ((size_t)(b * L_ + l0 + ll)) * C_ + c0 + c4);
            t[c4 + 0][ll] = v.x; t[c4 + 1][ll] = v.y;
            t[c4 + 2][ll] = v.z; t[c4 + 3][ll] = v.w;
        }
    }
    __syncthreads();
    {
        const int c = tid >> 4, l4 = (tid & 15) * 4;
        float* op = out + ((size_t)b * C_ + c0) * L_ + l0;
#pragma unroll
        for (int cc = c; cc < 64; cc += 16) {
            float4 v = {t[cc][l4], t[cc][l4 + 1], t[cc][l4 + 2], t[cc][l4 + 3]};
            *(float4*)(op + (size_t)cc * L_ + l4) = v;
        }
    }
}

__global__ __launch_bounds__(256) void cvt_bf16(const float* __restrict__ in,
                                                ushort* __restrict__ out, int n4)
{
    const int i = blockIdx.x * 256 + threadIdx.x;
    if (i < n4) {
        float4 v = *(const float4*)(in + 4 * (size_t)i);
        u16x4 o; o[0] = f2bf(v.x); o[1] = f2bf(v.y); o[2] = f2bf(v.z); o[3] = f2bf(v.w);
        *(u16x4*)(out + 4 * (size_t)i) = o;
    }
}

__global__ __launch_bounds__(256) void zero_kernel(float* __restrict__ p, int n4)
{
    const int i = blockIdx.x * 256 + threadIdx.x;
    if (i < n4) { float4 z = {0.f, 0.f, 0.f, 0.f}; *(float4*)(p + 4 * (size_t)i) = z; }
}

// ---------------------------------------------------------------------------
// conv_mfma: out[m,n] = act( sum_k A[m,k]*W[n,k] + bias[n] (+res[m,n]) )
// 128x128 tile, BK=32, 2-phase double-buffered global_load_lds pipeline
// (stage t+1 issued before compute of t; single vmcnt(0)+barrier per tile).
// MFMA operands SWAPPED (mfma(Wfrag, Afrag)) so each lane owns 4 consecutive
// output columns -> LDS-staged epilogue with coalesced 16B stores.
// ---------------------------------------------------------------------------
template<int ACT, bool HAS_RES>
__global__ __launch_bounds__(256) void conv_mfma(
    const ushort* __restrict__ A, const ushort* __restrict__ Wt,
    const float* __restrict__ bias, const ushort* __restrict__ res,
    ushort* __restrict__ out, int M, int N, int K)
{
    const int m0 = blockIdx.x * 128;
    const int n0 = blockIdx.y * 128;
    const int tid = threadIdx.x;
    const int w = tid >> 6, lane = tid & 63;
    const int wm = (w & 1) * 64, wn = (w >> 1) * 64;
    const int l16 = lane & 15, quad = lane >> 4;

    // 36 KB: K-loop dbuf [buf][A 4096 | B 4096] (32 KB), reused after the
    // K-loop as per-wave epilogue staging [4 waves][64 rows][72 ushorts].
    __shared__ ushort smem[18432];

    f32x4_t acc[4][4];
#pragma unroll
    for (int i = 0; i < 4; ++i)
#pragma unroll
        for (int j = 0; j < 4; ++j) acc[i][j] = (f32x4_t){0.f, 0.f, 0.f, 0.f};

    const int srow = lane >> 2;       // 0..15
    const int sslot = lane & 3;       // physical 16B slot

    // precomputed staging addresses (k-slot swizzle folded into global src)
    const ushort* gA[2]; const ushort* gB[2];
    ushort* lA[2]; ushort* lB[2];
#pragma unroll
    for (int r = 0; r < 2; ++r) {
        const int row = r * 64 + w * 16 + srow;
        const int lk = sslot ^ ((row >> 2) & 3);
        gA[r] = A  + (size_t)(m0 + row) * K + lk * 8;
        gB[r] = Wt + (size_t)(n0 + row) * K + lk * 8;
        lA[r] = smem + (r * 64 + w * 16) * 32;
        lB[r] = smem + 4096 + (r * 64 + w * 16) * 32;
    }

    const int nt = K >> 5;

    // prologue: stage tile 0 into buf 0
#pragma unroll
    for (int r = 0; r < 2; ++r) {
        GLOAD_LDS16(gA[r], lA[r]);
        GLOAD_LDS16(gB[r], lB[r]);
    }
    __syncthreads();   // compiler drains vmcnt(0) before s_barrier

    for (int t = 0; t < nt; ++t) {
        const int cur = t & 1;
        // issue next-tile loads first: in flight under this tile's compute
        if (t + 1 < nt) {
            const int nb = (cur ^ 1) * 8192;
            const size_t co = (size_t)(t + 1) * 32;
#pragma unroll
            for (int r = 0; r < 2; ++r) {
                GLOAD_LDS16(gA[r] + co, lA[r] + nb);
                GLOAD_LDS16(gB[r] + co, lB[r] + nb);
            }
        }
        const ushort* bA = smem + cur * 8192;
        const ushort* bB = bA + 4096;
        bf16x8_t amf[4], wf[4];
#pragma unroll
        for (int i = 0; i < 4; ++i) {
            const int arow = wm + i * 16 + l16;
            const int ap = quad ^ ((arow >> 2) & 3);
            amf[i] = *(const bf16x8_t*)(bA + arow * 32 + ap * 8);
            const int brow = wn + i * 16 + l16;
            const int bp = quad ^ ((brow >> 2) & 3);
            wf[i] = *(const bf16x8_t*)(bB + brow * 32 + bp * 8);
        }
        // swapped operands: D[row=n (quad*4+r)][col=m (l16)]
#pragma unroll
        for (int i = 0; i < 4; ++i)
#pragma unroll
            for (int j = 0; j < 4; ++j)
                acc[i][j] = __builtin_amdgcn_mfma_f32_16x16x32_bf16(wf[j], amf[i], acc[i][j], 0, 0, 0);
        if (t + 1 < nt) __syncthreads();
    }

    // ---- epilogue ----
    // acc[i][j][r] = C[m0+wm+i*16+l16][n0+wn+j*16+quad*4+r]: 4 consecutive
    // columns per lane. bias/res/act, pack bf16x4, stage per-wave 64x64 tile
    // in LDS ([m][n], 72-ushort row stride), then coalesced u16x8 stores.
    __syncthreads();                    // all waves done with K-loop LDS
    ushort* sT = smem + w * 4608;       // 64 * 72 ushorts per wave
#pragma unroll
    for (int j = 0; j < 4; ++j) {
        const int nb = wn + j * 16 + quad * 4;     // block-local n base
        const float4 bo = *(const float4*)(bias + n0 + nb);
        const float bv[4] = {bo.x, bo.y, bo.z, bo.w};
#pragma unroll
        for (int i = 0; i < 4; ++i) {
            const int ml = i * 16 + l16;           // wave-local m row
            float v[4];
#pragma unroll
            for (int r = 0; r < 4; ++r) v[r] = acc[i][j][r] + bv[r];
            if (HAS_RES) {
                const u16x4 rv = *(const u16x4*)(res + (size_t)(m0 + wm + ml) * N + n0 + nb);
#pragma unroll
                for (int r = 0; r < 4; ++r) v[r] += bf2f(rv[r]);
            }
            if (ACT == 1) {
#pragma unroll
                for (int r = 0; r < 4; ++r) v[r] = (v[r] > 0.f) ? v[r] : (__expf(v[r]) - 1.f);
            }
            u16x4 pv;
#pragma unroll
            for (int r = 0; r < 4; ++r) pv[r] = f2bf(v[r]);
            *(u16x4*)(sT + ml * 72 + (nb - wn)) = pv;
        }
    }
    // same-wave readback (wave-private region, no barrier needed)
    {
        const int rr = lane >> 3, ch = lane & 7;
#pragma unroll
        for (int rep = 0; rep < 8; ++rep) {
            const int ml = rep * 8 + rr;
            const u16x8 vo = *(const u16x8*)(sT + ml * 72 + ch * 8);
            *(u16x8*)(out + (size_t)(m0 + wm + ml) * N + n0 + wn + ch * 8) = vo;
        }
    }
}

// ---------------------------------------------------------------------------
// kstat_chunk: per-chunk column (max, expsum) of k [B*L, C] bf16.
// grid (C/64, B*8), 256 thr. Chunk = 512 rows. stats[b*C+c][ch] float2.
// ---------------------------------------------------------------------------
__global__ __launch_bounds__(256) void kstat_chunk(const ushort* __restrict__ k,
                                                   float2* __restrict__ stats)
{
    const int cg = blockIdx.x;            // col group (64 cols)
    const int bc = blockIdx.y;            // b*8 + ch
    const int b = bc >> 3, ch = bc & 7;
    const int tid = threadIdx.x;
    const int g = tid & 7;                // 8-col subgroup
    const int kk = tid >> 3;              // 0..31 row worker
    const int w = tid >> 6, lane = tid & 63;
    const ushort* base = k + ((size_t)(b * L_) + ch * 512) * C_ + cg * 64 + g * 8;

    __shared__ float red[4][8][8];
    __shared__ float mcol[64];

    float fm[8];
#pragma unroll
    for (int i = 0; i < 8; ++i) fm[i] = -3.0e38f;
    for (int r = kk; r < 512; r += 32) {
        u16x8 v = *(const u16x8*)(base + (size_t)r * C_);
#pragma unroll
        for (int i = 0; i < 8; ++i) fm[i] = fmaxf(fm[i], bf2f(v[i]));
    }
#pragma unroll
    for (int off = 8; off <= 32; off <<= 1)
#pragma unroll
        for (int i = 0; i < 8; ++i) fm[i] = fmaxf(fm[i], __shfl_xor(fm[i], off));
    if ((lane >> 3) == 0)
#pragma unroll
        for (int i = 0; i < 8; ++i) red[w][g][i] = fm[i];
    __syncthreads();
    if (tid < 64) {
        const int g2 = tid >> 3, j = tid & 7;
        mcol[g2 * 8 + j] = fmaxf(fmaxf(red[0][g2][j], red[1][g2][j]),
                                 fmaxf(red[2][g2][j], red[3][g2][j]));
    }
    __syncthreads();
    float fmc[8];
#pragma unroll
    for (int i = 0; i < 8; ++i) fmc[i] = mcol[g * 8 + i];

    float fs[8] = {};
    for (int r = kk; r < 512; r += 32) {
        u16x8 v = *(const u16x8*)(base + (size_t)r * C_);
#pragma unroll
        for (int i = 0; i < 8; ++i) fs[i] += __expf(bf2f(v[i]) - fmc[i]);
    }
#pragma unroll
    for (int off = 8; off <= 32; off <<= 1)
#pragma unroll
        for (int i = 0; i < 8; ++i) fs[i] += __shfl_xor(fs[i], off);
    __syncthreads();
    if ((lane >> 3) == 0)
#pragma unroll
        for (int i = 0; i < 8; ++i) red[w][g][i] = fs[i];
    __syncthreads();
    if (tid < 64) {
        const int g2 = tid >> 3, j = tid & 7;
        const float s = red[0][g2][j] + red[1][g2][j] + red[2][g2][j] + red[3][g2][j];
        const int c = cg * 64 + g2 * 8 + j;
        stats[((size_t)(b * C_ + c)) * 8 + ch] = make_float2(mcol[g2 * 8 + j], s);
    }
}

// ---------------------------------------------------------------------------
// kstat_merge: global (m, 1/S) per (b,c) from 8 chunk stats.
// ---------------------------------------------------------------------------
__global__ __launch_bounds__(256) void kstat_merge(const float2* __restrict__ stats,
                                                   float2* __restrict__ minv)
{
    const int i = blockIdx.x * 256 + threadIdx.x;
    if (i >= B_ * C_) return;
    float2 st[8];
    float m = -3.0e38f;
#pragma unroll
    for (int ch = 0; ch < 8; ++ch) { st[ch] = stats[(size_t)i * 8 + ch]; m = fmaxf(m, st[ch].x); }
    float s = 0.f;
#pragma unroll
    for (int ch = 0; ch < 8; ++ch) s += st[ch].y * __expf(st[ch].x - m);
    minv[i] = make_float2(m, 1.f / s);
}

// ---------------------------------------------------------------------------
// ctx_accum: ctxT[bh][dv][dk] += sum_l v[b,l,h*64+dv] * softmax_k[b,l,h*64+dk]
// k is RAW logits; softmax applied on the fly via minv. fp32 atomics.
// ---------------------------------------------------------------------------
__global__ __launch_bounds__(256) void ctx_accum(
    const ushort* __restrict__ kk, const ushort* __restrict__ vv,
    const float2* __restrict__ minv, float* __restrict__ ctx)
{
    const int bh = blockIdx.y, b = bh >> 3, h = bh & 7;
    const int l0 = blockIdx.x * 512;
    const int tid = threadIdx.x;
    __shared__ float sK[32][72];
    __shared__ float sV[32][72];
    const int srow = tid >> 3, c8 = (tid & 7) * 8;
    const int dv4 = (tid & 15) * 4, dk4 = (tid >> 4) * 4;

    float2 cst[8];
    {
        const float2* mp = minv + (size_t)b * C_ + h * 64 + c8;
#pragma unroll
        for (int i = 0; i < 8; ++i) cst[i] = mp[i];
    }
    float acc[4][4] = {};

    for (int lt = 0; lt < 512; lt += 32) {
        const size_t gbase = ((size_t)(b * L_ + l0 + lt + srow)) * C_ + h * 64 + c8;
        u16x8 kv = *(const u16x8*)(kk + gbase);
        u16x8 vvv = *(const u16x8*)(vv + gbase);
        __syncthreads();
#pragma unroll
        for (int i = 0; i < 8; ++i) {
            sK[srow][c8 + i] = __expf(bf2f(kv[i]) - cst[i].x) * cst[i].y;
            sV[srow][c8 + i] = bf2f(vvv[i]);
        }
        __syncthreads();
#pragma unroll
        for (int ll = 0; ll < 32; ++ll) {
            const float4 a = *(const float4*)&sV[ll][dv4];
            const float4 bb = *(const float4*)&sK[ll][dk4];
            const float av[4] = {a.x, a.y, a.z, a.w};
            const float bv[4] = {bb.x, bb.y, bb.z, bb.w};
#pragma unroll
            for (int i = 0; i < 4; ++i)
#pragma unroll
                for (int j = 0; j < 4; ++j)
                    acc[i][j] = fmaf(av[i], bv[j], acc[i][j]);
        }
    }
    float* cp = ctx + (size_t)bh * 4096;
#pragma unroll
    for (int i = 0; i < 4; ++i)
#pragma unroll
        for (int j = 0; j < 4; ++j)
            atomicAdd(&cp[(dv4 + i) * 64 + (dk4 + j)], acc[i][j]);
}

// ---------------------------------------------------------------------------
// att_mfma: att[b,l,h*64+dv] = sum_dk softmax_q[...dk] * ctxT[bh][dv][dk]
// q is RAW logits; per-row softmax over 64 dk fused into the staging loop
// (8 lanes/row shuffle-reduce). grid (L/128, B*H), 256 thr.
// ---------------------------------------------------------------------------
__global__ __launch_bounds__(256) void att_mfma(
    const ushort* __restrict__ q, const float* __restrict__ ctx,
    ushort* __restrict__ att)
{
    const int bh = blockIdx.y, b = bh >> 3, h = bh & 7;
    const int l0 = blockIdx.x * 128;
    const int tid = threadIdx.x, w = tid >> 6, lane = tid & 63;
    const int l16 = lane & 15, quad = lane >> 4;

    __shared__ ushort sQ[128 * 72];   // [l][dk]
    __shared__ ushort sC[64 * 72];    // [dv][dk]

    {
        const int part = tid & 7;
#pragma unroll
        for (int rr = tid >> 3; rr < 128; rr += 32) {
            u16x8 v = *(const u16x8*)(q + ((size_t)(b * L_ + l0 + rr)) * C_ + h * 64 + part * 8);
            float f[8], m = -3.0e38f;
#pragma unroll
            for (int i = 0; i < 8; ++i) { f[i] = bf2f(v[i]); m = fmaxf(m, f[i]); }
            m = fmaxf(m, __shfl_xor(m, 1));
            m = fmaxf(m, __shfl_xor(m, 2));
            m = fmaxf(m, __shfl_xor(m, 4));
            float s = 0.f;
#pragma unroll
            for (int i = 0; i < 8; ++i) { f[i] = __expf(f[i] - m); s += f[i]; }
            s += __shfl_xor(s, 1); s += __shfl_xor(s, 2); s += __shfl_xor(s, 4);
            const float inv = 1.f / s;
            u16x8 o;
#pragma unroll
            for (int i = 0; i < 8; ++i) o[i] = f2bf(f[i] * inv);
            *(u16x8*)(sQ + rr * 72 + part * 8) = o;
        }
        const int dv = tid >> 2, dk0 = (tid & 3) * 16;
        const float* cp = ctx + (size_t)bh * 4096 + dv * 64 + dk0;
#pragma unroll
        for (int i = 0; i < 16; ++i) sC[dv * 72 + dk0 + i] = f2bf(cp[i]);
    }
    __syncthreads();

    f32x4_t acc[2][4];
#pragma unroll
    for (int i = 0; i < 2; ++i)
#pragma unroll
        for (int j = 0; j < 4; ++j) acc[i][j] = (f32x4_t){0.f, 0.f, 0.f, 0.f};

#pragma unroll
    for (int ks = 0; ks < 2; ++ks) {
        const int k0 = ks * 32;
        bf16x8_t aq[2], bc[4];
#pragma unroll
        for (int i = 0; i < 2; ++i)
            aq[i] = *(const bf16x8_t*)(sQ + (w * 32 + i * 16 + l16) * 72 + k0 + quad * 8);
#pragma unroll
        for (int j = 0; j < 4; ++j)
            bc[j] = *(const bf16x8_t*)(sC + (j * 16 + l16) * 72 + k0 + quad * 8);
#pragma unroll
        for (int i = 0; i < 2; ++i)
#pragma unroll
            for (int j = 0; j < 4; ++j)
                acc[i][j] = __builtin_amdgcn_mfma_f32_16x16x32_bf16(aq[i], bc[j], acc[i][j], 0, 0, 0);
    }

#pragma unroll
    for (int j = 0; j < 4; ++j)
#pragma unroll
        for (int i = 0; i < 2; ++i) {
            const int mb = l0 + w * 32 + i * 16 + quad * 4;
#pragma unroll
            for (int r = 0; r < 4; ++r)
                att[((size_t)(b * L_ + mb + r)) * C_ + h * 64 + j * 16 + l16] = f2bf(acc[i][j][r]);
        }
}

// ---------------------------------------------------------------------------
// LayerNorm over 512 contiguous channels; wave per row.
// ---------------------------------------------------------------------------
template<bool OUTF32>
__global__ __launch_bounds__(256) void ln_row(
    const ushort* __restrict__ in, const float* __restrict__ g,
    const float* __restrict__ be, ushort* __restrict__ outb,
    float* __restrict__ outf)
{
    const int tid = threadIdx.x, w = tid >> 6, lane = tid & 63;
    const size_t row = (size_t)blockIdx.x * 4 + w;
    const ushort* p = in + row * C_ + lane * 8;
    u16x8 v = *(const u16x8*)p;
    float f[8], s = 0.f, s2 = 0.f;
#pragma unroll
    for (int i = 0; i < 8; ++i) { f[i] = bf2f(v[i]); s += f[i]; s2 = fmaf(f[i], f[i], s2); }
#pragma unroll
    for (int o = 1; o < 64; o <<= 1) { s += __shfl_xor(s, o); s2 += __shfl_xor(s2, o); }
    const float mean = s * (1.f / C_);
    const float var  = s2 * (1.f / C_) - mean * mean;
    const float inv  = rsqrtf(var + 1e-5f);
    if (OUTF32) {
        float* op = outf + row * C_ + lane * 8;
#pragma unroll
        for (int i = 0; i < 8; ++i)
            op[i] = (f[i] - mean) * inv * g[lane * 8 + i] + be[lane * 8 + i];
    } else {
        u16x8 ov;
#pragma unroll
        for (int i = 0; i < 8; ++i)
            ov[i] = f2bf((f[i] - mean) * inv * g[lane * 8 + i] + be[lane * 8 + i]);
        *(u16x8*)(outb + row * C_ + lane * 8) = ov;
    }
}

// ---------------------------------------------------------------------------
extern "C" void kernel_launch(void* const* d_in, const int* in_sizes, int n_in,
                              void* d_out, int out_size, void* d_ws, size_t ws_size,
                              hipStream_t stream)
{
    const float* z1  = (const float*)d_in[0];
    const float* z2  = (const float*)d_in[1];
    const float* Wq  = (const float*)d_in[2];
    const float* bq  = (const float*)d_in[3];
    const float* Wk  = (const float*)d_in[4];
    const float* bk  = (const float*)d_in[5];
    const float* Wv  = (const float*)d_in[6];
    const float* bv  = (const float*)d_in[7];
    const float* Wr  = (const float*)d_in[8];
    const float* br  = (const float*)d_in[9];
    const float* g1  = (const float*)d_in[10];
    const float* be1 = (const float*)d_in[11];
    const float* W1  = (const float*)d_in[12];
    const float* b1  = (const float*)d_in[13];
    const float* W2  = (const float*)d_in[14];
    const float* b2  = (const float*)d_in[15];
    const float* g2  = (const float*)d_in[16];
    const float* be2 = (const float*)d_in[17];
    float* out = (float*)d_out;

    const size_t SB = (size_t)B_ * L_ * C_;     // 16.78M elems per bf16 buffer
    ushort* ws16 = (ushort*)d_ws;
    ushort* b0v = ws16;            // z1t -> y
    ushort* b1v = ws16 + SB;       // z2t -> att
    ushort* b2v = ws16 + 2 * SB;   // q(raw) -> z -> yf32(lo)
    ushort* b3v = ws16 + 3 * SB;   // k(raw) -> x -> yf32(hi)
    ushort* wb  = ws16 + 4 * SB;   // bf16 weights (4MB)
    ushort* wbq = wb;
    ushort* wbk = wb + 262144;
    ushort* wbv = wb + 524288;
    ushort* wbr = wb + 786432;
    ushort* wb1 = wb + 1048576;
    ushort* wb2 = wb + 1572864;
    float*  ctxf = (float*)(wb + 2097152);       // [B*H,64,64] fp32 (256KB)
    float2* stats = (float2*)(ctxf + 65536);     // [B*C][8] (256KB)
    float2* minv  = stats + (size_t)B_ * C_ * 8; // [B*C] (32KB)
    ushort* vbuf = (ushort*)d_out;               // v lives in d_out
    ushort* hbuf = (ushort*)d_out;               // h: [B*L, 1024] bf16
    float*  yf32 = (float*)b2v;                  // spans b2v+b3v

    const dim3 blk(256);
    const int M = B_ * L_;   // 32768

    // 0) input transposes + weight casts
    transpose_in<<<dim3(L_/64, C_/64, B_), blk, 0, stream>>>(z1, b0v);
    transpose_in<<<dim3(L_/64, C_/64, B_), blk, 0, stream>>>(z2, b1v);
    cvt_bf16<<<dim3(262144/4/256), blk, 0, stream>>>(Wq, wbq, 262144/4);
    cvt_bf16<<<dim3(262144/4/256), blk, 0, stream>>>(Wk, wbk, 262144/4);
    cvt_bf16<<<dim3(262144/4/256), blk, 0, stream>>>(Wv, wbv, 262144/4);
    cvt_bf16<<<dim3(262144/4/256), blk, 0, stream>>>(Wr, wbr, 262144/4);
    cvt_bf16<<<dim3(524288/4/256), blk, 0, stream>>>(W1, wb1, 524288/4);
    cvt_bf16<<<dim3(524288/4/256), blk, 0, stream>>>(W2, wb2, 524288/4);

    // 1) projections (MFMA); q and k stay RAW logits
    conv_mfma<0,false><<<dim3(M/128, C_/128), blk, 0, stream>>>(b0v, wbq, bq, nullptr, b2v, M, C_, C_);
    conv_mfma<0,false><<<dim3(M/128, C_/128), blk, 0, stream>>>(b1v, wbk, bk, nullptr, b3v, M, C_, C_);
    conv_mfma<0,false><<<dim3(M/128, C_/128), blk, 0, stream>>>(b1v, wbv, bv, nullptr, vbuf, M, C_, C_);

    // 2) k-softmax stats (parallel, chunked)
    kstat_chunk<<<dim3(C_/64, B_ * 8), blk, 0, stream>>>(b3v, stats);
    kstat_merge<<<dim3((B_ * C_ + 255) / 256), blk, 0, stream>>>(stats, minv);

    // 3) ctxT = V^T softmax(K)  (softmax fused, fp32 atomics over 8 l-splits)
    zero_kernel<<<dim3(65536/256), blk, 0, stream>>>(ctxf, 65536);
    ctx_accum<<<dim3(8, B_ * H_), blk, 0, stream>>>(b3v, vbuf, minv, ctxf);

    // 4) att = softmax(q) . ctxT^T per head (q-softmax fused); att -> b1v
    att_mfma<<<dim3(L_/128, B_ * H_), blk, 0, stream>>>(b2v, ctxf, b1v);

    // 5) z = Wr@att + br + z1t  -> b2v (q dead)
    conv_mfma<0,true><<<dim3(M/128, C_/128), blk, 0, stream>>>(b1v, wbr, br, b0v, b2v, M, C_, C_);

    // 6) x = LN1(z) -> b3v (k dead)
    ln_row<false><<<dim3(M/4), blk, 0, stream>>>(b2v, g1, be1, b3v, nullptr);

    // 7) h = ELU(W1@x) -> d_out (v dead)
    conv_mfma<1,false><<<dim3(M/128, C2_/128), blk, 0, stream>>>(b3v, wb1, b1, nullptr, hbuf, M, C2_, C_);

    // 8) y = W2@h -> b0v (z1t dead)
    conv_mfma<0,false><<<dim3(M/128, C_/128), blk, 0, stream>>>(hbuf, wb2, b2, nullptr, b0v, M, C_, C2_);

    // 9) LN2 -> fp32 [B*L,C] into b2v+b3v region (z,x dead)
    ln_row<true><<<dim3(M/4), blk, 0, stream>>>(b0v, g2, be2, nullptr, yf32);

    // 10) transpose to [B,C,L] fp32 -> d_out (h dead)
    transpose_out<<<dim3(L_/64, C_/64, B_), blk, 0, stream>>>(yf32, out);
}